// Round 16
// baseline (200.790 us; speedup 1.0000x reference)
//
#include <hip/hip_runtime.h>
#include <stdint.h>
#include <math.h>

typedef __attribute__((ext_vector_type(8))) __bf16 bf16x8;
typedef __attribute__((ext_vector_type(4))) __bf16 bf16x4;
typedef __attribute__((ext_vector_type(4))) float f32x4;
typedef __attribute__((ext_vector_type(8))) short short8;

#define MFMA(a, b, c) __builtin_amdgcn_mfma_f32_16x16x32_bf16((a), (b), (c), 0, 0, 0)

constexpr int DIMC  = 1024;
constexpr int HEADS = 16;
constexpr int HD    = 64;
constexpr int BATCH = 4;
constexpr int SEQ   = 1370;
constexpr int MROWS = BATCH * SEQ;      // 5480
constexpr int NPAD  = 1408;             // 22*64
// QK scale folded with log2(e) so softmax runs in exp2 domain
constexpr float QK_SCALE = 0.125f * 1.44269504088896341f;

__device__ __forceinline__ unsigned short f2bf(float f) {
    union { float f; unsigned int u; } v; v.f = f;
    unsigned int r = (v.u + 0x7FFFu + ((v.u >> 16) & 1u)) >> 16;
    return (unsigned short)r;
}

__device__ __forceinline__ void gl2lds16(const unsigned short* g, unsigned short* l) {
    __builtin_amdgcn_global_load_lds(
        (const __attribute__((address_space(1))) unsigned int*)g,
        (__attribute__((address_space(3))) unsigned int*)l,
        16, 0, 0);
}

// ---------------- fused prep: cast x, transpose both weights, zero v-pad ----------------
__device__ __forceinline__ void transpose_tile(const float* __restrict__ in,
                                               unsigned short* __restrict__ out,
                                               int R, int C, int cb, int rb) {
    __shared__ float tile[32][33];
    int tx = threadIdx.x & 31, ty = threadIdx.x >> 5;   // 32 x 8
    int cbase = cb * 32, rbase = rb * 32;
#pragma unroll
    for (int rr = 0; rr < 4; ++rr) {
        int r = ty + rr * 8;
        tile[r][tx] = in[(size_t)(rbase + r) * C + cbase + tx];
    }
    __syncthreads();
#pragma unroll
    for (int rr = 0; rr < 4; ++rr) {
        int cr = ty + rr * 8;
        out[(size_t)(cbase + cr) * R + rbase + tx] = f2bf(tile[tx][cr]);
    }
}

__global__ __launch_bounds__(256) void prep_kernel(const float* __restrict__ x,
                                                   unsigned short* __restrict__ xb,
                                                   const float* __restrict__ w_qkv,
                                                   unsigned short* __restrict__ wqkvT,
                                                   const float* __restrict__ w_proj,
                                                   unsigned short* __restrict__ wprojT,
                                                   unsigned short* __restrict__ vTg) {
    int bid = blockIdx.x;
    if (bid < 2740) {
        int i = bid * 256 + threadIdx.x;            // nvec = 701440 = 2740*256 exactly
        f32x4 a = reinterpret_cast<const f32x4*>(x)[2 * i];
        f32x4 b = reinterpret_cast<const f32x4*>(x)[2 * i + 1];
        short8 o;
        o[0] = (short)f2bf(a[0]); o[1] = (short)f2bf(a[1]);
        o[2] = (short)f2bf(a[2]); o[3] = (short)f2bf(a[3]);
        o[4] = (short)f2bf(b[0]); o[5] = (short)f2bf(b[1]);
        o[6] = (short)f2bf(b[2]); o[7] = (short)f2bf(b[3]);
        reinterpret_cast<short8*>(xb)[i] = o;
    } else if (bid < 2740 + 3072) {
        int b = bid - 2740;                         // w_qkv: C=3072 (96 cb), R=1024 (32 rb)
        transpose_tile(w_qkv, wqkvT, 1024, 3072, b % 96, b / 96);
    } else if (bid < 2740 + 3072 + 1024) {
        int b = bid - (2740 + 3072);                // w_proj: 32 x 32
        transpose_tile(w_proj, wprojT, 1024, 1024, b % 32, b / 32);
    } else {
        int idx = (bid - 6836) * 256 + threadIdx.x; // 64*64*38 = 155648 = 608*256 exactly
        const int padw = NPAD - SEQ;                // 38
        int col = SEQ + idx % padw;
        int rowflat = idx / padw;                   // bh*64 + d
        vTg[(size_t)rowflat * NPAD + col] = 0;
    }
}

// ------------- gemm1 (QKV): 128x256xBK64, 8 waves (2Mx4N), per-wave 64x64 -------------
// Grid 43x12 = 516 blocks at 1 block/CU (96KB LDS) = 2.02 balanced CU-rounds (no r14 tail).
// 32 MFMA/wave per K-step (4x r9's barrier amortization; FLOP/LDS-byte 21.8 -> 32).
// T4 counted-vmcnt, distance-2 prefetch into the just-freed buffer:
//   compute(buf[cur]) -> barrier -> stage(kt+2 -> buf[cur]) -> vmcnt(6) -> barrier
// The 6 newest loads stay in flight ACROSS the barrier with a full K-step to land; never
// vmcnt(0) mid-loop. Race-safe: restage only after the barrier all readers passed (their
// ds_reads retired before MFMA issue); uniform barrier counts across waves.
// LDS swizzle: 8 x 16B slots/row, slot = kc ^ (row&7); source pre-swizzled (linear DMA
// dest, rule #21) and ds_read XORs the same involution -> 2-way banks (free).
__global__ __launch_bounds__(512, 2) void gemm_qkv_kernel(const unsigned short* __restrict__ A,
                                                          const unsigned short* __restrict__ Bt,
                                                          int M, int N, int K,
                                                          const float* __restrict__ bias,
                                                          unsigned short* __restrict__ qg,
                                                          unsigned short* __restrict__ kg,
                                                          unsigned short* __restrict__ vTg) {
    __shared__ unsigned short As[2][128 * 64];   // 16KB per buf
    __shared__ unsigned short Bs[2][256 * 64];   // 32KB per buf  -> 96KB total
    const int tid = threadIdx.x;
    const int l = tid & 63, w = tid >> 6;        // w 0..7
    const int wr = w & 1, wc = w >> 1;           // wave tile: rows 64*wr, cols 64*wc
    const int lm = l & 15, lk = l >> 4;

    const int bx = blockIdx.x % 12, by = blockIdx.x / 12;
    const int brow = by * 128, bcol = bx * 256;

    f32x4 acc[4][4];
#pragma unroll
    for (int i = 0; i < 4; ++i)
#pragma unroll
        for (int j = 0; j < 4; ++j) acc[i][j] = f32x4{0.f, 0.f, 0.f, 0.f};

    auto stage = [&](int kt, int buf) {
#pragma unroll
        for (int q = 0; q < 2; ++q) {            // A: 1024 x 16B chunks, 2/thread
            int cid = q * 512 + tid;
            int row = cid >> 3, kc = cid & 7;
            int src = ((kc ^ (row & 7)) << 3);
            int ga = min(brow + row, M - 1);
            gl2lds16(&A[(size_t)ga * K + kt * 64 + src], &As[buf][cid * 8]);
        }
#pragma unroll
        for (int q = 0; q < 4; ++q) {            // B: 2048 x 16B chunks, 4/thread
            int cid = q * 512 + tid;
            int row = cid >> 3, kc = cid & 7;
            int src = ((kc ^ (row & 7)) << 3);
            int gb = bcol + row;                 // N multiple of 256
            gl2lds16(&Bt[(size_t)gb * K + kt * 64 + src], &Bs[buf][cid * 8]);
        }
    };

    const int nkt = K >> 6;                      // 16
    stage(0, 0);
    stage(1, 1);                                 // 12 loads/thread in flight
    asm volatile("s_waitcnt vmcnt(6)" ::: "memory");   // buf0's 6 retired
    __builtin_amdgcn_s_barrier();

    for (int kt = 0; kt < nkt; ++kt) {
        const int cur = kt & 1;
        // frag reads: row&7 == lm&7 for all frag rows (offsets are multiples of 16)
        bf16x8 af[4][2], bfr[4][2];
#pragma unroll
        for (int i = 0; i < 4; ++i)
#pragma unroll
            for (int ks = 0; ks < 2; ++ks) {
                int row = wr * 64 + i * 16 + lm;
                int slot = (ks * 4 + lk) ^ (lm & 7);
                af[i][ks] = *reinterpret_cast<const bf16x8*>(&As[cur][row * 64 + slot * 8]);
            }
#pragma unroll
        for (int j = 0; j < 4; ++j)
#pragma unroll
            for (int ks = 0; ks < 2; ++ks) {
                int row = wc * 64 + j * 16 + lm;
                int slot = (ks * 4 + lk) ^ (lm & 7);
                bfr[j][ks] = *reinterpret_cast<const bf16x8*>(&Bs[cur][row * 64 + slot * 8]);
            }
        __builtin_amdgcn_s_setprio(1);
#pragma unroll
        for (int i = 0; i < 4; ++i)
#pragma unroll
            for (int j = 0; j < 4; ++j)
#pragma unroll
                for (int ks = 0; ks < 2; ++ks)
                    acc[i][j] = MFMA(af[i][ks], bfr[j][ks], acc[i][j]);
        __builtin_amdgcn_s_setprio(0);

        __builtin_amdgcn_s_barrier();            // all reads of buf[cur] consumed
        if (kt + 2 < nkt) {
            stage(kt + 2, cur);                  // refill freed buffer; 6 loads in flight
            asm volatile("s_waitcnt vmcnt(6)" ::: "memory");  // buf[cur^1] complete
        } else if (kt + 1 < nkt) {
            asm volatile("s_waitcnt vmcnt(0)" ::: "memory");
        }
        if (kt + 1 < nkt) __builtin_amdgcn_s_barrier();
    }

    // epilogue: scatter QKV. C frag: row = lk*4+r, col = lm
#pragma unroll
    for (int i = 0; i < 4; ++i) {
        int mbase = brow + wr * 64 + i * 16 + lk * 4;
#pragma unroll
        for (int j = 0; j < 4; ++j) {
            int col = bcol + wc * 64 + j * 16 + lm;
            float bv = bias[col];
            int which = col >> 10;              // 0:q 1:k 2:v
            int head = (col >> 6) & 15;
            int d = col & 63;
#pragma unroll
            for (int r = 0; r < 4; ++r) {
                int m = mbase + r;
                if (m >= M) continue;
                float val = acc[i][j][r] + bv;
                int b = m / SEQ;
                int nseq = m - b * SEQ;
                int bh = b * HEADS + head;
                if (which == 0) {
                    qg[((size_t)bh * SEQ + nseq) * HD + d] = f2bf(val * QK_SCALE);
                } else if (which == 1) {
                    kg[((size_t)bh * SEQ + nseq) * HD + d] = f2bf(val);
                } else {
                    vTg[((size_t)bh * HD + d) * NPAD + nseq] = f2bf(val);
                }
            }
        }
    }
}

// ------------- gemm2 (proj): r9-exact — 8-wave 128x128, BK=32, 2-buf 32KB -------------
__global__ __launch_bounds__(512) void gemm_proj_kernel(const unsigned short* __restrict__ A,
                                                        const unsigned short* __restrict__ Bt,
                                                        int M, int N, int K, int Nx,
                                                        const float* __restrict__ bias,
                                                        float* __restrict__ outf) {
    __shared__ unsigned short As[2][128 * 32];
    __shared__ unsigned short Bs[2][128 * 32];
    const int tid = threadIdx.x;
    const int l = tid & 63, w = tid >> 6;
    const int wr = w >> 2, wc = w & 3;           // wave tile: rows 64*wr, cols 32*wc
    const int lm = l & 15, lk = l >> 4;

    int nwg = gridDim.x;
    int wgid = (blockIdx.x & 7) * (nwg >> 3) + (blockIdx.x >> 3);
    int bx = wgid % Nx, by = wgid / Nx;
    const int brow = by * 128, bcol = bx * 128;

    f32x4 acc[4][2];
#pragma unroll
    for (int i = 0; i < 4; ++i)
#pragma unroll
        for (int j = 0; j < 2; ++j) acc[i][j] = f32x4{0.f, 0.f, 0.f, 0.f};

    const int srow = tid >> 2;
    const int ssrc = (((tid & 3) ^ ((srow >> 1) & 3)) << 3);
    auto stage = [&](int kt, int buf) {
        int ga = min(brow + srow, M - 1);
        gl2lds16(&A[(size_t)ga * K + kt * 32 + ssrc], &As[buf][tid * 8]);
        int gb = bcol + srow;
        gl2lds16(&Bt[(size_t)gb * K + kt * 32 + ssrc], &Bs[buf][tid * 8]);
    };

    const int nkt = K >> 5;
    stage(0, 0);
    __syncthreads();
    int cur = 0;
    for (int kt = 0; kt < nkt; ++kt) {
        if (kt + 1 < nkt) stage(kt + 1, cur ^ 1);

        const int swa = (lk ^ ((lm >> 1) & 3)) * 8;
        bf16x8 af[4], bfr[2];
#pragma unroll
        for (int i = 0; i < 4; ++i)
            af[i] = *reinterpret_cast<const bf16x8*>(&As[cur][(wr * 64 + i * 16 + lm) * 32 + swa]);
#pragma unroll
        for (int j = 0; j < 2; ++j)
            bfr[j] = *reinterpret_cast<const bf16x8*>(&Bs[cur][(wc * 32 + j * 16 + lm) * 32 + swa]);
        __builtin_amdgcn_s_setprio(1);
#pragma unroll
        for (int i = 0; i < 4; ++i)
#pragma unroll
            for (int j = 0; j < 2; ++j)
                acc[i][j] = MFMA(af[i], bfr[j], acc[i][j]);
        __builtin_amdgcn_s_setprio(0);
        __syncthreads();
        cur ^= 1;
    }

#pragma unroll
    for (int i = 0; i < 4; ++i) {
        int mbase = brow + wr * 64 + i * 16 + lk * 4;
#pragma unroll
        for (int j = 0; j < 2; ++j) {
            int col = bcol + wc * 32 + j * 16 + lm;
            float bv = bias[col];
#pragma unroll
            for (int r = 0; r < 4; ++r) {
                int m = mbase + r;
                if (m >= M) continue;
                outf[(size_t)m * DIMC + col] = acc[i][j][r] + bv;
            }
        }
    }
}

// ---------------- flash attention (r9-exact): 128 q-rows / block (8 waves), KV tiles of 64 ----------------
__global__ __launch_bounds__(512) void attn_kernel(const unsigned short* __restrict__ qg,
                                                   const unsigned short* __restrict__ kg,
                                                   const unsigned short* __restrict__ vTg,
                                                   unsigned short* __restrict__ ao) {
    __shared__ unsigned short Ks[64 * 72];     // [kv][d], stride 72
    __shared__ unsigned short Vs[64 * 72];     // [d][kv] (V transposed)
    __shared__ unsigned short Pw[8][16 * 72];  // per-wave P relay [q][kv]

    const int tid = threadIdx.x;
    const int l = tid & 63, w = tid >> 6;      // w 0..7
    const int lm = l & 15, lk = l >> 4;

    // XCD-aware bijective swizzle: 704 blocks = 8 XCDs x 88
    int wg = (blockIdx.x & 7) * 88 + (blockIdx.x >> 3);
    const int bh = wg / 11;                    // 0..63
    const int qbase = (wg - bh * 11) * 128;

    // Q fragment: lane holds Q[q=lm][d=lk*8..]
    int qr = min(qbase + w * 16 + lm, SEQ - 1);
    const unsigned short* qp = &qg[((size_t)bh * SEQ + qr) * HD + lk * 8];
    bf16x8 qf0 = *reinterpret_cast<const bf16x8*>(qp);
    bf16x8 qf1 = *reinterpret_cast<const bf16x8*>(qp + 32);

    f32x4 o[4];
#pragma unroll
    for (int jd = 0; jd < 4; ++jd) o[jd] = f32x4{0.f, 0.f, 0.f, 0.f};
    float mrun = -INFINITY, lrun = 0.f;        // lrun = per-lane PARTIAL row sum

    // staging: 512 threads cover 64 rows x 8 chunks of 16B for each of K and V
    const int r0 = tid >> 3;                   // 0..63
    const int c8b = (tid & 7) << 3;            // 0..56
    const unsigned short* kbase = &kg[(size_t)bh * SEQ * HD];
    const unsigned short* vbase = &vTg[(size_t)bh * HD * NPAD];

    short8 kr, vr;
    auto load_tile = [&](int t) {
        int kvg = min(t * 64 + r0, SEQ - 1);
        kr = *reinterpret_cast<const short8*>(&kbase[(size_t)kvg * HD + c8b]);
        vr = *reinterpret_cast<const short8*>(&vbase[(size_t)r0 * NPAD + t * 64 + c8b]);
    };
    auto write_tile = [&]() {
        *reinterpret_cast<short8*>(&Ks[r0 * 72 + c8b]) = kr;
        *reinterpret_cast<short8*>(&Vs[r0 * 72 + c8b]) = vr;
    };

    const int NT = (SEQ + 63) >> 6;   // 22
    load_tile(0);
    for (int t = 0; t < NT; ++t) {
        write_tile();                 // waits on in-flight loads, writes LDS
        __syncthreads();
        if (t + 1 < NT) load_tile(t + 1);   // in flight during compute

        // S^T = K Q^T : s[j][r] = S[kv = j*16 + lk*4 + r][q = lm]
        f32x4 s[4];
        __builtin_amdgcn_s_setprio(1);
#pragma unroll
        for (int j = 0; j < 4; ++j) {
            f32x4 z = {0.f, 0.f, 0.f, 0.f};
            bf16x8 k0 = *reinterpret_cast<const bf16x8*>(&Ks[(j * 16 + lm) * 72 + lk * 8]);
            bf16x8 k1 = *reinterpret_cast<const bf16x8*>(&Ks[(j * 16 + lm) * 72 + 32 + lk * 8]);
            z = MFMA(k0, qf0, z);
            z = MFMA(k1, qf1, z);
            s[j] = z;
        }
        __builtin_amdgcn_s_setprio(0);

        // mask only in the tail tile
        if (t == NT - 1) {
#pragma unroll
            for (int j = 0; j < 4; ++j)
#pragma unroll
                for (int r = 0; r < 4; ++r) {
                    int kvg = t * 64 + j * 16 + lk * 4 + r;
                    if (kvg >= SEQ) s[j][r] = -INFINITY;
                }
        }

        // per-lane tile max (no shuffles)
        float tmax = s[0][0];
#pragma unroll
        for (int j = 0; j < 4; ++j)
#pragma unroll
            for (int r = 0; r < 4; ++r) tmax = fmaxf(tmax, s[j][r]);

        // deferred exact-max: slow path only when some lane's max grew past mrun+8.
        if (!__all(tmax - mrun <= 8.0f)) {
            float tm = fmaxf(tmax, __shfl_xor(tmax, 16));
            tm = fmaxf(tm, __shfl_xor(tm, 32));
            float mnew = fmaxf(mrun, tm);
            float scale = exp2f(mrun - mnew);
            mrun = mnew;
            lrun *= scale;
            float sc[4];
#pragma unroll
            for (int r = 0; r < 4; ++r) sc[r] = __shfl(scale, lk * 4 + r);
#pragma unroll
            for (int jd = 0; jd < 4; ++jd) {
                o[jd][0] *= sc[0]; o[jd][1] *= sc[1];
                o[jd][2] *= sc[2]; o[jd][3] *= sc[3];
            }
        }

        float p[4][4];
        float psum = 0.f;
#pragma unroll
        for (int j = 0; j < 4; ++j)
#pragma unroll
            for (int r = 0; r < 4; ++r) {
                float pv = exp2f(s[j][r] - mrun);
                p[j][r] = pv;
                psum += pv;
            }
        lrun += psum;                 // per-lane partial; reduced once at the end

        // relay P through LDS: Pw[q=lm][kv], packed 4xbf16 writes (kv contiguous)
#pragma unroll
        for (int j = 0; j < 4; ++j) {
            bf16x4 pk;
            pk[0] = (__bf16)p[j][0]; pk[1] = (__bf16)p[j][1];
            pk[2] = (__bf16)p[j][2]; pk[3] = (__bf16)p[j][3];
            *reinterpret_cast<bf16x4*>(&Pw[w][lm * 72 + j * 16 + lk * 4]) = pk;
        }

        bf16x8 pa0 = *reinterpret_cast<const bf16x8*>(&Pw[w][lm * 72 + lk * 8]);
        bf16x8 pa1 = *reinterpret_cast<const bf16x8*>(&Pw[w][lm * 72 + 32 + lk * 8]);
        __builtin_amdgcn_s_setprio(1);
#pragma unroll
        for (int jd = 0; jd < 4; ++jd) {
            bf16x8 v0 = *reinterpret_cast<const bf16x8*>(&Vs[(jd * 16 + lm) * 72 + lk * 8]);
            bf16x8 v1 = *reinterpret_cast<const bf16x8*>(&Vs[(jd * 16 + lm) * 72 + 32 + lk * 8]);
            o[jd] = MFMA(pa0, v0, o[jd]);
            o[jd] = MFMA(pa1, v1, o[jd]);
        }
        __builtin_amdgcn_s_setprio(0);
        __syncthreads();
    }

    // epilogue: reduce lrun across the 4 lk lanes once, normalize, write bf16
    float ltot = lrun;
    ltot += __shfl_xor(ltot, 16);
    ltot += __shfl_xor(ltot, 32);
    float linv = 1.f / ltot;
    int b = bh >> 4, h = bh & 15;
#pragma unroll
    for (int r = 0; r < 4; ++r) {
        int q = qbase + w * 16 + lk * 4 + r;
        float inv = __shfl(linv, lk * 4 + r);
        if (q >= SEQ) continue;
#pragma unroll
        for (int jd = 0; jd < 4; ++jd) {
            ao[((size_t)b * SEQ + q) * DIMC + h * HD + jd * 16 + lm] = f2bf(o[jd][r] * inv);
        }
    }
}

extern "C" void kernel_launch(void* const* d_in, const int* in_sizes, int n_in,
                              void* d_out, int out_size, void* d_ws, size_t ws_size,
                              hipStream_t stream) {
    const float* x      = (const float*)d_in[0];
    const float* w_qkv  = (const float*)d_in[1];
    const float* b_qkv  = (const float*)d_in[2];
    const float* w_proj = (const float*)d_in[3];
    const float* b_proj = (const float*)d_in[4];
    float* out = (float*)d_out;

    char* ws = (char*)d_ws;
    unsigned short* xb     = (unsigned short*)ws; ws += (size_t)MROWS * DIMC * 2;
    unsigned short* wqkvT  = (unsigned short*)ws; ws += (size_t)3 * DIMC * DIMC * 2;
    unsigned short* wprojT = (unsigned short*)ws; ws += (size_t)DIMC * DIMC * 2;
    unsigned short* qg     = (unsigned short*)ws; ws += (size_t)64 * SEQ * HD * 2;
    unsigned short* kg     = (unsigned short*)ws; ws += (size_t)64 * SEQ * HD * 2;
    unsigned short* vTg    = (unsigned short*)ws; ws += (size_t)64 * HD * NPAD * 2;
    unsigned short* ao     = (unsigned short*)ws; ws += (size_t)MROWS * DIMC * 2;

    // fused prep: cast x (2740) + transpose w_qkv (3072) + transpose w_proj (1024) + vpad (608)
    prep_kernel<<<dim3(7444), 256, 0, stream>>>(x, xb, w_qkv, wqkvT, w_proj, wprojT, vTg);

    // gemm1 (QKV): 128x256 tiles -> 43 M-tiles x 12 N-tiles = 516 blocks (2.02 CU rounds)
    gemm_qkv_kernel<<<dim3(43 * 12), 512, 0, stream>>>(
        xb, wqkvT, MROWS, 3 * DIMC, DIMC, b_qkv, qg, kg, vTg);

    attn_kernel<<<dim3(8 * 88), 512, 0, stream>>>(qg, kg, vTg, ao);

    // gemm2 (proj): r9 config — 8 N-tiles x 43 M-tiles = 344 blocks
    gemm_proj_kernel<<<dim3(8 * 43), 512, 0, stream>>>(
        ao, wprojT, MROWS, DIMC, DIMC, 8, b_proj, out);
}

// Round 17
// 180.024 us; speedup vs baseline: 1.1153x; 1.1153x over previous
//
#include <hip/hip_runtime.h>
#include <stdint.h>
#include <math.h>

typedef __attribute__((ext_vector_type(8))) __bf16 bf16x8;
typedef __attribute__((ext_vector_type(4))) __bf16 bf16x4;
typedef __attribute__((ext_vector_type(4))) float f32x4;
typedef __attribute__((ext_vector_type(8))) short short8;

#define MFMA(a, b, c) __builtin_amdgcn_mfma_f32_16x16x32_bf16((a), (b), (c), 0, 0, 0)

constexpr int DIMC  = 1024;
constexpr int HEADS = 16;
constexpr int HD    = 64;
constexpr int BATCH = 4;
constexpr int SEQ   = 1370;
constexpr int MROWS = BATCH * SEQ;      // 5480
constexpr int NPAD  = 1408;             // 22*64
// QK scale folded with log2(e) so softmax runs in exp2 domain
constexpr float QK_SCALE = 0.125f * 1.44269504088896341f;

__device__ __forceinline__ unsigned short f2bf(float f) {
    union { float f; unsigned int u; } v; v.f = f;
    unsigned int r = (v.u + 0x7FFFu + ((v.u >> 16) & 1u)) >> 16;
    return (unsigned short)r;
}

__device__ __forceinline__ void gl2lds16(const unsigned short* g, unsigned short* l) {
    __builtin_amdgcn_global_load_lds(
        (const __attribute__((address_space(1))) unsigned int*)g,
        (__attribute__((address_space(3))) unsigned int*)l,
        16, 0, 0);
}

// ---------------- fused prep: cast x, transpose both weights, zero v-pad ----------------
__device__ __forceinline__ void transpose_tile(const float* __restrict__ in,
                                               unsigned short* __restrict__ out,
                                               int R, int C, int cb, int rb) {
    __shared__ float tile[32][33];
    int tx = threadIdx.x & 31, ty = threadIdx.x >> 5;   // 32 x 8
    int cbase = cb * 32, rbase = rb * 32;
#pragma unroll
    for (int rr = 0; rr < 4; ++rr) {
        int r = ty + rr * 8;
        tile[r][tx] = in[(size_t)(rbase + r) * C + cbase + tx];
    }
    __syncthreads();
#pragma unroll
    for (int rr = 0; rr < 4; ++rr) {
        int cr = ty + rr * 8;
        out[(size_t)(cbase + cr) * R + rbase + tx] = f2bf(tile[tx][cr]);
    }
}

__global__ __launch_bounds__(256) void prep_kernel(const float* __restrict__ x,
                                                   unsigned short* __restrict__ xb,
                                                   const float* __restrict__ w_qkv,
                                                   unsigned short* __restrict__ wqkvT,
                                                   const float* __restrict__ w_proj,
                                                   unsigned short* __restrict__ wprojT,
                                                   unsigned short* __restrict__ vTg) {
    int bid = blockIdx.x;
    if (bid < 2740) {
        int i = bid * 256 + threadIdx.x;            // nvec = 701440 = 2740*256 exactly
        f32x4 a = reinterpret_cast<const f32x4*>(x)[2 * i];
        f32x4 b = reinterpret_cast<const f32x4*>(x)[2 * i + 1];
        short8 o;
        o[0] = (short)f2bf(a[0]); o[1] = (short)f2bf(a[1]);
        o[2] = (short)f2bf(a[2]); o[3] = (short)f2bf(a[3]);
        o[4] = (short)f2bf(b[0]); o[5] = (short)f2bf(b[1]);
        o[6] = (short)f2bf(b[2]); o[7] = (short)f2bf(b[3]);
        reinterpret_cast<short8*>(xb)[i] = o;
    } else if (bid < 2740 + 3072) {
        int b = bid - 2740;                         // w_qkv: C=3072 (96 cb), R=1024 (32 rb)
        transpose_tile(w_qkv, wqkvT, 1024, 3072, b % 96, b / 96);
    } else if (bid < 2740 + 3072 + 1024) {
        int b = bid - (2740 + 3072);                // w_proj: 32 x 32
        transpose_tile(w_proj, wprojT, 1024, 1024, b % 32, b / 32);
    } else {
        int idx = (bid - 6836) * 256 + threadIdx.x; // 64*64*38 = 155648 = 608*256 exactly
        const int padw = NPAD - SEQ;                // 38
        int col = SEQ + idx % padw;
        int rowflat = idx / padw;                   // bh*64 + d
        vTg[(size_t)rowflat * NPAD + col] = 0;
    }
}

// ---------------- bf16 GEMM: 256-thread / 4-wave re-partition of the r9 structure ----------------
// 128x128 tile, BK=32, 2-buf 32KB LDS, per-wave 64x64 (acc 4x4, 16 MFMA/step).
// vs r9 (512thr/8 waves): barrier granularity halves (only 4 waves drain together; other
// resident blocks compute through), MFMA:ds_read doubles (16:8 vs 8:6). Same proven
// async stage (gl2lds, source pre-swizzle) + zero-conflict XOR'd read + XCD swizzle.
// EPI 0: scatter into q (scaled), k, vT buffers.  EPI 1: fp32 output + bias.
template <int EPI>
__global__ __launch_bounds__(256) void gemm_bt_kernel(const unsigned short* __restrict__ A,
                                                      const unsigned short* __restrict__ Bt,
                                                      int M, int N, int K, int Nx,
                                                      const float* __restrict__ bias,
                                                      unsigned short* __restrict__ qg,
                                                      unsigned short* __restrict__ kg,
                                                      unsigned short* __restrict__ vTg,
                                                      float* __restrict__ outf) {
    __shared__ unsigned short As[2][128 * 32];   // linear 64B rows (4 swizzled 16B slots)
    __shared__ unsigned short Bs[2][128 * 32];
    const int tid = threadIdx.x;
    const int l = tid & 63, w = tid >> 6;        // w 0..3
    const int wr = w >> 1, wc = w & 1;           // wave tile: rows 64*wr, cols 64*wc
    const int lm = l & 15, lk = l >> 4;

    // XCD-bijective swizzle (grid is 1-D, count divisible by 8)
    int nwg = gridDim.x;
    int wgid = (blockIdx.x & 7) * (nwg >> 3) + (blockIdx.x >> 3);
    int bx = wgid % Nx, by = wgid / Nx;
    const int brow = by * 128, bcol = bx * 128;

    f32x4 acc[4][4];
#pragma unroll
    for (int i = 0; i < 4; ++i)
#pragma unroll
        for (int j = 0; j < 4; ++j) acc[i][j] = f32x4{0.f, 0.f, 0.f, 0.f};

    auto stage = [&](int kt, int buf) {
#pragma unroll
        for (int q = 0; q < 2; ++q) {            // 512 chunks per operand, 2/thread
            int cid = q * 256 + tid;
            int row = cid >> 2, kc = cid & 3;
            int src = ((kc ^ ((row >> 1) & 3)) << 3);   // pre-swizzled source chunk
            int ga = min(brow + row, M - 1);
            gl2lds16(&A[(size_t)ga * K + kt * 32 + src], &As[buf][cid * 8]);
            int gb = bcol + row;                 // N is a multiple of 128
            gl2lds16(&Bt[(size_t)gb * K + kt * 32 + src], &Bs[buf][cid * 8]);
        }
    };

    const int nkt = K >> 5;
    stage(0, 0);
    __syncthreads();
    int cur = 0;
    for (int kt = 0; kt < nkt; ++kt) {
        if (kt + 1 < nkt) stage(kt + 1, cur ^ 1);    // async, in flight during compute

        const int swa = (lk ^ ((lm >> 1) & 3)) * 8;  // swizzled read chunk
        bf16x8 af[4], bfr[4];
#pragma unroll
        for (int i = 0; i < 4; ++i)
            af[i] = *reinterpret_cast<const bf16x8*>(&As[cur][(wr * 64 + i * 16 + lm) * 32 + swa]);
#pragma unroll
        for (int j = 0; j < 4; ++j)
            bfr[j] = *reinterpret_cast<const bf16x8*>(&Bs[cur][(wc * 64 + j * 16 + lm) * 32 + swa]);
        __builtin_amdgcn_s_setprio(1);
#pragma unroll
        for (int i = 0; i < 4; ++i)
#pragma unroll
            for (int j = 0; j < 4; ++j)
                acc[i][j] = MFMA(af[i], bfr[j], acc[i][j]);
        __builtin_amdgcn_s_setprio(0);
        __syncthreads();                              // drains staging vmcnt + barrier
        cur ^= 1;
    }

    // epilogue: C layout per fragment -> row=(lk*4+r), col=lm
#pragma unroll
    for (int i = 0; i < 4; ++i) {
        int mbase = brow + wr * 64 + i * 16 + lk * 4;
#pragma unroll
        for (int j = 0; j < 4; ++j) {
            int col = bcol + wc * 64 + j * 16 + lm;
            float bv = bias[col];
#pragma unroll
            for (int r = 0; r < 4; ++r) {
                int m = mbase + r;
                if (m >= M) continue;
                float val = acc[i][j][r] + bv;
                if constexpr (EPI == 0) {
                    int which = col >> 10;          // 0:q 1:k 2:v
                    int head = (col >> 6) & 15;
                    int d = col & 63;
                    int b = m / SEQ;
                    int nseq = m - b * SEQ;
                    int bh = b * HEADS + head;
                    if (which == 0) {
                        qg[((size_t)bh * SEQ + nseq) * HD + d] = f2bf(val * QK_SCALE);
                    } else if (which == 1) {
                        kg[((size_t)bh * SEQ + nseq) * HD + d] = f2bf(val);
                    } else {
                        vTg[((size_t)bh * HD + d) * NPAD + nseq] = f2bf(val);
                    }
                } else {
                    outf[(size_t)m * DIMC + col] = val;
                }
            }
        }
    }
}

// ---------------- flash attention (r9-exact): 128 q-rows / block (8 waves), KV tiles of 64 ----------------
__global__ __launch_bounds__(512) void attn_kernel(const unsigned short* __restrict__ qg,
                                                   const unsigned short* __restrict__ kg,
                                                   const unsigned short* __restrict__ vTg,
                                                   unsigned short* __restrict__ ao) {
    __shared__ unsigned short Ks[64 * 72];     // [kv][d], stride 72
    __shared__ unsigned short Vs[64 * 72];     // [d][kv] (V transposed)
    __shared__ unsigned short Pw[8][16 * 72];  // per-wave P relay [q][kv]

    const int tid = threadIdx.x;
    const int l = tid & 63, w = tid >> 6;      // w 0..7
    const int lm = l & 15, lk = l >> 4;

    // XCD-aware bijective swizzle: 704 blocks = 8 XCDs x 88
    int wg = (blockIdx.x & 7) * 88 + (blockIdx.x >> 3);
    const int bh = wg / 11;                    // 0..63
    const int qbase = (wg - bh * 11) * 128;

    // Q fragment: lane holds Q[q=lm][d=lk*8..]
    int qr = min(qbase + w * 16 + lm, SEQ - 1);
    const unsigned short* qp = &qg[((size_t)bh * SEQ + qr) * HD + lk * 8];
    bf16x8 qf0 = *reinterpret_cast<const bf16x8*>(qp);
    bf16x8 qf1 = *reinterpret_cast<const bf16x8*>(qp + 32);

    f32x4 o[4];
#pragma unroll
    for (int jd = 0; jd < 4; ++jd) o[jd] = f32x4{0.f, 0.f, 0.f, 0.f};
    float mrun = -INFINITY, lrun = 0.f;        // lrun = per-lane PARTIAL row sum

    // staging: 512 threads cover 64 rows x 8 chunks of 16B for each of K and V
    const int r0 = tid >> 3;                   // 0..63
    const int c8b = (tid & 7) << 3;            // 0..56
    const unsigned short* kbase = &kg[(size_t)bh * SEQ * HD];
    const unsigned short* vbase = &vTg[(size_t)bh * HD * NPAD];

    short8 kr, vr;
    auto load_tile = [&](int t) {
        int kvg = min(t * 64 + r0, SEQ - 1);
        kr = *reinterpret_cast<const short8*>(&kbase[(size_t)kvg * HD + c8b]);
        vr = *reinterpret_cast<const short8*>(&vbase[(size_t)r0 * NPAD + t * 64 + c8b]);
    };
    auto write_tile = [&]() {
        *reinterpret_cast<short8*>(&Ks[r0 * 72 + c8b]) = kr;
        *reinterpret_cast<short8*>(&Vs[r0 * 72 + c8b]) = vr;
    };

    const int NT = (SEQ + 63) >> 6;   // 22
    load_tile(0);
    for (int t = 0; t < NT; ++t) {
        write_tile();                 // waits on in-flight loads, writes LDS
        __syncthreads();
        if (t + 1 < NT) load_tile(t + 1);   // in flight during compute

        // S^T = K Q^T : s[j][r] = S[kv = j*16 + lk*4 + r][q = lm]
        f32x4 s[4];
        __builtin_amdgcn_s_setprio(1);
#pragma unroll
        for (int j = 0; j < 4; ++j) {
            f32x4 z = {0.f, 0.f, 0.f, 0.f};
            bf16x8 k0 = *reinterpret_cast<const bf16x8*>(&Ks[(j * 16 + lm) * 72 + lk * 8]);
            bf16x8 k1 = *reinterpret_cast<const bf16x8*>(&Ks[(j * 16 + lm) * 72 + 32 + lk * 8]);
            z = MFMA(k0, qf0, z);
            z = MFMA(k1, qf1, z);
            s[j] = z;
        }
        __builtin_amdgcn_s_setprio(0);

        // mask only in the tail tile
        if (t == NT - 1) {
#pragma unroll
            for (int j = 0; j < 4; ++j)
#pragma unroll
                for (int r = 0; r < 4; ++r) {
                    int kvg = t * 64 + j * 16 + lk * 4 + r;
                    if (kvg >= SEQ) s[j][r] = -INFINITY;
                }
        }

        // per-lane tile max (no shuffles)
        float tmax = s[0][0];
#pragma unroll
        for (int j = 0; j < 4; ++j)
#pragma unroll
            for (int r = 0; r < 4; ++r) tmax = fmaxf(tmax, s[j][r]);

        // deferred exact-max: slow path only when some lane's max grew past mrun+8.
        if (!__all(tmax - mrun <= 8.0f)) {
            float tm = fmaxf(tmax, __shfl_xor(tmax, 16));
            tm = fmaxf(tm, __shfl_xor(tm, 32));
            float mnew = fmaxf(mrun, tm);
            float scale = exp2f(mrun - mnew);
            mrun = mnew;
            lrun *= scale;
            float sc[4];
#pragma unroll
            for (int r = 0; r < 4; ++r) sc[r] = __shfl(scale, lk * 4 + r);
#pragma unroll
            for (int jd = 0; jd < 4; ++jd) {
                o[jd][0] *= sc[0]; o[jd][1] *= sc[1];
                o[jd][2] *= sc[2]; o[jd][3] *= sc[3];
            }
        }

        float p[4][4];
        float psum = 0.f;
#pragma unroll
        for (int j = 0; j < 4; ++j)
#pragma unroll
            for (int r = 0; r < 4; ++r) {
                float pv = exp2f(s[j][r] - mrun);
                p[j][r] = pv;
                psum += pv;
            }
        lrun += psum;                 // per-lane partial; reduced once at the end

        // relay P through LDS: Pw[q=lm][kv], packed 4xbf16 writes (kv contiguous)
#pragma unroll
        for (int j = 0; j < 4; ++j) {
            bf16x4 pk;
            pk[0] = (__bf16)p[j][0]; pk[1] = (__bf16)p[j][1];
            pk[2] = (__bf16)p[j][2]; pk[3] = (__bf16)p[j][3];
            *reinterpret_cast<bf16x4*>(&Pw[w][lm * 72 + j * 16 + lk * 4]) = pk;
        }

        bf16x8 pa0 = *reinterpret_cast<const bf16x8*>(&Pw[w][lm * 72 + lk * 8]);
        bf16x8 pa1 = *reinterpret_cast<const bf16x8*>(&Pw[w][lm * 72 + 32 + lk * 8]);
        __builtin_amdgcn_s_setprio(1);
#pragma unroll
        for (int jd = 0; jd < 4; ++jd) {
            bf16x8 v0 = *reinterpret_cast<const bf16x8*>(&Vs[(jd * 16 + lm) * 72 + lk * 8]);
            bf16x8 v1 = *reinterpret_cast<const bf16x8*>(&Vs[(jd * 16 + lm) * 72 + 32 + lk * 8]);
            o[jd] = MFMA(pa0, v0, o[jd]);
            o[jd] = MFMA(pa1, v1, o[jd]);
        }
        __builtin_amdgcn_s_setprio(0);
        __syncthreads();
    }

    // epilogue: reduce lrun across the 4 lk lanes once, normalize, write bf16
    float ltot = lrun;
    ltot += __shfl_xor(ltot, 16);
    ltot += __shfl_xor(ltot, 32);
    float linv = 1.f / ltot;
    int b = bh >> 4, h = bh & 15;
#pragma unroll
    for (int r = 0; r < 4; ++r) {
        int q = qbase + w * 16 + lk * 4 + r;
        float inv = __shfl(linv, lk * 4 + r);
        if (q >= SEQ) continue;
#pragma unroll
        for (int jd = 0; jd < 4; ++jd) {
            ao[((size_t)b * SEQ + q) * DIMC + h * HD + jd * 16 + lm] = f2bf(o[jd][r] * inv);
        }
    }
}

extern "C" void kernel_launch(void* const* d_in, const int* in_sizes, int n_in,
                              void* d_out, int out_size, void* d_ws, size_t ws_size,
                              hipStream_t stream) {
    const float* x      = (const float*)d_in[0];
    const float* w_qkv  = (const float*)d_in[1];
    const float* b_qkv  = (const float*)d_in[2];
    const float* w_proj = (const float*)d_in[3];
    const float* b_proj = (const float*)d_in[4];
    float* out = (float*)d_out;

    char* ws = (char*)d_ws;
    unsigned short* xb     = (unsigned short*)ws; ws += (size_t)MROWS * DIMC * 2;
    unsigned short* wqkvT  = (unsigned short*)ws; ws += (size_t)3 * DIMC * DIMC * 2;
    unsigned short* wprojT = (unsigned short*)ws; ws += (size_t)DIMC * DIMC * 2;
    unsigned short* qg     = (unsigned short*)ws; ws += (size_t)64 * SEQ * HD * 2;
    unsigned short* kg     = (unsigned short*)ws; ws += (size_t)64 * SEQ * HD * 2;
    unsigned short* vTg    = (unsigned short*)ws; ws += (size_t)64 * HD * NPAD * 2;
    unsigned short* ao     = (unsigned short*)ws; ws += (size_t)MROWS * DIMC * 2;

    // fused prep: cast x (2740) + transpose w_qkv (3072) + transpose w_proj (1024) + vpad (608)
    prep_kernel<<<dim3(7444), 256, 0, stream>>>(x, xb, w_qkv, wqkvT, w_proj, wprojT, vTg);

    // gemm1: grid 24 x 43 = 1032 blocks (divisible by 8), 1-D launch + internal swizzle
    gemm_bt_kernel<0><<<dim3(24 * 43), 256, 0, stream>>>(
        xb, wqkvT, MROWS, 3 * DIMC, DIMC, 24, b_qkv, qg, kg, vTg, nullptr);

    attn_kernel<<<dim3(8 * 88), 512, 0, stream>>>(qg, kg, vTg, ao);

    // gemm2: grid 8 x 43 = 344 blocks (divisible by 8)
    gemm_bt_kernel<1><<<dim3(8 * 43), 256, 0, stream>>>(
        ao, wprojT, MROWS, DIMC, DIMC, 8, b_proj, nullptr, nullptr, nullptr, out);
}

// Round 18
// 172.297 us; speedup vs baseline: 1.1654x; 1.0448x over previous
//
#include <hip/hip_runtime.h>
#include <stdint.h>
#include <math.h>

typedef __attribute__((ext_vector_type(8))) __bf16 bf16x8;
typedef __attribute__((ext_vector_type(4))) __bf16 bf16x4;
typedef __attribute__((ext_vector_type(4))) float f32x4;
typedef __attribute__((ext_vector_type(8))) short short8;

#define MFMA(a, b, c) __builtin_amdgcn_mfma_f32_16x16x32_bf16((a), (b), (c), 0, 0, 0)

constexpr int DIMC  = 1024;
constexpr int HEADS = 16;
constexpr int HD    = 64;
constexpr int BATCH = 4;
constexpr int SEQ   = 1370;
constexpr int MROWS = BATCH * SEQ;      // 5480
constexpr int NPAD  = 1408;             // 22*64
// QK scale folded with log2(e) so softmax runs in exp2 domain
constexpr float QK_SCALE = 0.125f * 1.44269504088896341f;

__device__ __forceinline__ unsigned short f2bf(float f) {
    union { float f; unsigned int u; } v; v.f = f;
    unsigned int r = (v.u + 0x7FFFu + ((v.u >> 16) & 1u)) >> 16;
    return (unsigned short)r;
}

__device__ __forceinline__ void gl2lds16(const unsigned short* g, unsigned short* l) {
    __builtin_amdgcn_global_load_lds(
        (const __attribute__((address_space(1))) unsigned int*)g,
        (__attribute__((address_space(3))) unsigned int*)l,
        16, 0, 0);
}

// ---------------- fused prep: cast x, transpose both weights, zero v-pad ----------------
__device__ __forceinline__ void transpose_tile(const float* __restrict__ in,
                                               unsigned short* __restrict__ out,
                                               int R, int C, int cb, int rb) {
    __shared__ float tile[32][33];
    int tx = threadIdx.x & 31, ty = threadIdx.x >> 5;   // 32 x 8
    int cbase = cb * 32, rbase = rb * 32;
#pragma unroll
    for (int rr = 0; rr < 4; ++rr) {
        int r = ty + rr * 8;
        tile[r][tx] = in[(size_t)(rbase + r) * C + cbase + tx];
    }
    __syncthreads();
#pragma unroll
    for (int rr = 0; rr < 4; ++rr) {
        int cr = ty + rr * 8;
        out[(size_t)(cbase + cr) * R + rbase + tx] = f2bf(tile[tx][cr]);
    }
}

__global__ __launch_bounds__(256) void prep_kernel(const float* __restrict__ x,
                                                   unsigned short* __restrict__ xb,
                                                   const float* __restrict__ w_qkv,
                                                   unsigned short* __restrict__ wqkvT,
                                                   const float* __restrict__ w_proj,
                                                   unsigned short* __restrict__ wprojT,
                                                   unsigned short* __restrict__ vTg) {
    int bid = blockIdx.x;
    if (bid < 2740) {
        int i = bid * 256 + threadIdx.x;            // nvec = 701440 = 2740*256 exactly
        f32x4 a = reinterpret_cast<const f32x4*>(x)[2 * i];
        f32x4 b = reinterpret_cast<const f32x4*>(x)[2 * i + 1];
        short8 o;
        o[0] = (short)f2bf(a[0]); o[1] = (short)f2bf(a[1]);
        o[2] = (short)f2bf(a[2]); o[3] = (short)f2bf(a[3]);
        o[4] = (short)f2bf(b[0]); o[5] = (short)f2bf(b[1]);
        o[6] = (short)f2bf(b[2]); o[7] = (short)f2bf(b[3]);
        reinterpret_cast<short8*>(xb)[i] = o;
    } else if (bid < 2740 + 3072) {
        int b = bid - 2740;                         // w_qkv: C=3072 (96 cb), R=1024 (32 rb)
        transpose_tile(w_qkv, wqkvT, 1024, 3072, b % 96, b / 96);
    } else if (bid < 2740 + 3072 + 1024) {
        int b = bid - (2740 + 3072);                // w_proj: 32 x 32
        transpose_tile(w_proj, wprojT, 1024, 1024, b % 32, b / 32);
    } else {
        int idx = (bid - 6836) * 256 + threadIdx.x; // 64*64*38 = 155648 = 608*256 exactly
        const int padw = NPAD - SEQ;                // 38
        int col = SEQ + idx % padw;
        int rowflat = idx / padw;                   // bh*64 + d
        vTg[(size_t)rowflat * NPAD + col] = 0;
    }
}

// ---------------- bf16 GEMM (r9-exact): C[M,N] = A[M,K] * Bt[N,K]^T (+bias) ----------------
// 8-wave (512-thread) 128x128 tile, BK=32, 2-buf 32KB LDS, per-wave 64x32; ~4 blocks/CU
// (wave-limited) for cross-block latency hiding. Staging = 1 global_load_lds per thread per
// operand with source pre-swizzle; reads use the matching XOR'd chunk (0 bank conflicts).
// EPI 0: scatter into q (scaled), k, vT buffers.  EPI 1: fp32 output + bias.
template <int EPI>
__global__ __launch_bounds__(512) void gemm_bt_kernel(const unsigned short* __restrict__ A,
                                                      const unsigned short* __restrict__ Bt,
                                                      int M, int N, int K, int Nx,
                                                      const float* __restrict__ bias,
                                                      unsigned short* __restrict__ qg,
                                                      unsigned short* __restrict__ kg,
                                                      unsigned short* __restrict__ vTg,
                                                      float* __restrict__ outf) {
    __shared__ unsigned short As[2][128 * 32];   // linear 64B rows (4 swizzled 16B slots)
    __shared__ unsigned short Bs[2][128 * 32];
    const int tid = threadIdx.x;
    const int l = tid & 63, w = tid >> 6;        // w 0..7
    const int wr = w >> 2, wc = w & 3;           // wave tile: rows 64*wr, cols 32*wc
    const int lm = l & 15, lk = l >> 4;

    // XCD-bijective swizzle (grid is 1-D, count divisible by 8)
    int nwg = gridDim.x;
    int wgid = (blockIdx.x & 7) * (nwg >> 3) + (blockIdx.x >> 3);
    int bx = wgid % Nx, by = wgid / Nx;
    const int brow = by * 128, bcol = bx * 128;

    f32x4 acc[4][2];
#pragma unroll
    for (int i = 0; i < 4; ++i)
#pragma unroll
        for (int j = 0; j < 2; ++j) acc[i][j] = f32x4{0.f, 0.f, 0.f, 0.f};

    const int srow = tid >> 2;                               // 0..127
    const int ssrc = (((tid & 3) ^ ((srow >> 1) & 3)) << 3); // pre-swizzled source chunk
    auto stage = [&](int kt, int buf) {
        int ga = min(brow + srow, M - 1);
        gl2lds16(&A[(size_t)ga * K + kt * 32 + ssrc], &As[buf][tid * 8]);
        int gb = bcol + srow;                    // N is a multiple of 128
        gl2lds16(&Bt[(size_t)gb * K + kt * 32 + ssrc], &Bs[buf][tid * 8]);
    };

    const int nkt = K >> 5;
    stage(0, 0);
    __syncthreads();
    int cur = 0;
    for (int kt = 0; kt < nkt; ++kt) {
        if (kt + 1 < nkt) stage(kt + 1, cur ^ 1);    // async, in flight during compute

        const int swa = (lk ^ ((lm >> 1) & 3)) * 8;  // swizzled read chunk
        bf16x8 af[4], bfr[2];
#pragma unroll
        for (int i = 0; i < 4; ++i)
            af[i] = *reinterpret_cast<const bf16x8*>(&As[cur][(wr * 64 + i * 16 + lm) * 32 + swa]);
#pragma unroll
        for (int j = 0; j < 2; ++j)
            bfr[j] = *reinterpret_cast<const bf16x8*>(&Bs[cur][(wc * 32 + j * 16 + lm) * 32 + swa]);
        __builtin_amdgcn_s_setprio(1);
#pragma unroll
        for (int i = 0; i < 4; ++i)
#pragma unroll
            for (int j = 0; j < 2; ++j)
                acc[i][j] = MFMA(af[i], bfr[j], acc[i][j]);
        __builtin_amdgcn_s_setprio(0);
        __syncthreads();                              // drains staging vmcnt + barrier
        cur ^= 1;
    }

    // epilogue: C layout per fragment -> row=(lk*4+r), col=lm
#pragma unroll
    for (int i = 0; i < 4; ++i) {
        int mbase = brow + wr * 64 + i * 16 + lk * 4;
#pragma unroll
        for (int j = 0; j < 2; ++j) {
            int col = bcol + wc * 32 + j * 16 + lm;
            float bv = bias[col];
#pragma unroll
            for (int r = 0; r < 4; ++r) {
                int m = mbase + r;
                if (m >= M) continue;
                float val = acc[i][j][r] + bv;
                if constexpr (EPI == 0) {
                    int which = col >> 10;          // 0:q 1:k 2:v
                    int head = (col >> 6) & 15;
                    int d = col & 63;
                    int b = m / SEQ;
                    int nseq = m - b * SEQ;
                    int bh = b * HEADS + head;
                    if (which == 0) {
                        qg[((size_t)bh * SEQ + nseq) * HD + d] = f2bf(val * QK_SCALE);
                    } else if (which == 1) {
                        kg[((size_t)bh * SEQ + nseq) * HD + d] = f2bf(val);
                    } else {
                        vTg[((size_t)bh * HD + d) * NPAD + nseq] = f2bf(val);
                    }
                } else {
                    outf[(size_t)m * DIMC + col] = val;
                }
            }
        }
    }
}

// ---------------- flash attention (r9-exact): 128 q-rows / block (8 waves), KV tiles of 64 ----------------
// Swapped QK^T: S = mfma(K, Q) -> S[kv][q], each lane owns ONE q-row (q = lm).
// K/V staged in LDS (latency amortization across 8 waves); tile t+1 reg-prefetched
// during compute of t (T14). Deferred cross-lane max: fast path has ZERO shuffles
// (mrun uniform-per-row invariant); lrun kept as per-lane partials, reduced once at end.
__global__ __launch_bounds__(512) void attn_kernel(const unsigned short* __restrict__ qg,
                                                   const unsigned short* __restrict__ kg,
                                                   const unsigned short* __restrict__ vTg,
                                                   unsigned short* __restrict__ ao) {
    __shared__ unsigned short Ks[64 * 72];     // [kv][d], stride 72
    __shared__ unsigned short Vs[64 * 72];     // [d][kv] (V transposed)
    __shared__ unsigned short Pw[8][16 * 72];  // per-wave P relay [q][kv]

    const int tid = threadIdx.x;
    const int l = tid & 63, w = tid >> 6;      // w 0..7
    const int lm = l & 15, lk = l >> 4;

    // XCD-aware bijective swizzle: 704 blocks = 8 XCDs x 88
    int wg = (blockIdx.x & 7) * 88 + (blockIdx.x >> 3);
    const int bh = wg / 11;                    // 0..63
    const int qbase = (wg - bh * 11) * 128;

    // Q fragment: lane holds Q[q=lm][d=lk*8..]
    int qr = min(qbase + w * 16 + lm, SEQ - 1);
    const unsigned short* qp = &qg[((size_t)bh * SEQ + qr) * HD + lk * 8];
    bf16x8 qf0 = *reinterpret_cast<const bf16x8*>(qp);
    bf16x8 qf1 = *reinterpret_cast<const bf16x8*>(qp + 32);

    f32x4 o[4];
#pragma unroll
    for (int jd = 0; jd < 4; ++jd) o[jd] = f32x4{0.f, 0.f, 0.f, 0.f};
    float mrun = -INFINITY, lrun = 0.f;        // lrun = per-lane PARTIAL row sum

    // staging: 512 threads cover 64 rows x 8 chunks of 16B for each of K and V
    const int r0 = tid >> 3;                   // 0..63
    const int c8b = (tid & 7) << 3;            // 0..56
    const unsigned short* kbase = &kg[(size_t)bh * SEQ * HD];
    const unsigned short* vbase = &vTg[(size_t)bh * HD * NPAD];

    short8 kr, vr;
    auto load_tile = [&](int t) {
        int kvg = min(t * 64 + r0, SEQ - 1);
        kr = *reinterpret_cast<const short8*>(&kbase[(size_t)kvg * HD + c8b]);
        vr = *reinterpret_cast<const short8*>(&vbase[(size_t)r0 * NPAD + t * 64 + c8b]);
    };
    auto write_tile = [&]() {
        *reinterpret_cast<short8*>(&Ks[r0 * 72 + c8b]) = kr;
        *reinterpret_cast<short8*>(&Vs[r0 * 72 + c8b]) = vr;
    };

    const int NT = (SEQ + 63) >> 6;   // 22
    load_tile(0);
    for (int t = 0; t < NT; ++t) {
        write_tile();                 // waits on in-flight loads, writes LDS
        __syncthreads();
        if (t + 1 < NT) load_tile(t + 1);   // in flight during compute

        // S^T = K Q^T : s[j][r] = S[kv = j*16 + lk*4 + r][q = lm]
        f32x4 s[4];
        __builtin_amdgcn_s_setprio(1);
#pragma unroll
        for (int j = 0; j < 4; ++j) {
            f32x4 z = {0.f, 0.f, 0.f, 0.f};
            bf16x8 k0 = *reinterpret_cast<const bf16x8*>(&Ks[(j * 16 + lm) * 72 + lk * 8]);
            bf16x8 k1 = *reinterpret_cast<const bf16x8*>(&Ks[(j * 16 + lm) * 72 + 32 + lk * 8]);
            z = MFMA(k0, qf0, z);
            z = MFMA(k1, qf1, z);
            s[j] = z;
        }
        __builtin_amdgcn_s_setprio(0);

        // mask only in the tail tile
        if (t == NT - 1) {
#pragma unroll
            for (int j = 0; j < 4; ++j)
#pragma unroll
                for (int r = 0; r < 4; ++r) {
                    int kvg = t * 64 + j * 16 + lk * 4 + r;
                    if (kvg >= SEQ) s[j][r] = -INFINITY;
                }
        }

        // per-lane tile max (no shuffles)
        float tmax = s[0][0];
#pragma unroll
        for (int j = 0; j < 4; ++j)
#pragma unroll
            for (int r = 0; r < 4; ++r) tmax = fmaxf(tmax, s[j][r]);

        // deferred exact-max: slow path only when some lane's max grew past mrun+8.
        // Invariant: mrun is uniform across the 4 lanes of each row.
        if (!__all(tmax - mrun <= 8.0f)) {
            float tm = fmaxf(tmax, __shfl_xor(tmax, 16));
            tm = fmaxf(tm, __shfl_xor(tm, 32));
            float mnew = fmaxf(mrun, tm);
            float scale = exp2f(mrun - mnew);
            mrun = mnew;
            lrun *= scale;
            float sc[4];
#pragma unroll
            for (int r = 0; r < 4; ++r) sc[r] = __shfl(scale, lk * 4 + r);
#pragma unroll
            for (int jd = 0; jd < 4; ++jd) {
                o[jd][0] *= sc[0]; o[jd][1] *= sc[1];
                o[jd][2] *= sc[2]; o[jd][3] *= sc[3];
            }
        }

        float p[4][4];
        float psum = 0.f;
#pragma unroll
        for (int j = 0; j < 4; ++j)
#pragma unroll
            for (int r = 0; r < 4; ++r) {
                float pv = exp2f(s[j][r] - mrun);
                p[j][r] = pv;
                psum += pv;
            }
        lrun += psum;                 // per-lane partial; reduced once at the end

        // relay P through LDS: Pw[q=lm][kv], packed 4xbf16 writes (kv contiguous)
#pragma unroll
        for (int j = 0; j < 4; ++j) {
            bf16x4 pk;
            pk[0] = (__bf16)p[j][0]; pk[1] = (__bf16)p[j][1];
            pk[2] = (__bf16)p[j][2]; pk[3] = (__bf16)p[j][3];
            *reinterpret_cast<bf16x4*>(&Pw[w][lm * 72 + j * 16 + lk * 4]) = pk;
        }

        bf16x8 pa0 = *reinterpret_cast<const bf16x8*>(&Pw[w][lm * 72 + lk * 8]);
        bf16x8 pa1 = *reinterpret_cast<const bf16x8*>(&Pw[w][lm * 72 + 32 + lk * 8]);
        __builtin_amdgcn_s_setprio(1);
#pragma unroll
        for (int jd = 0; jd < 4; ++jd) {
            bf16x8 v0 = *reinterpret_cast<const bf16x8*>(&Vs[(jd * 16 + lm) * 72 + lk * 8]);
            bf16x8 v1 = *reinterpret_cast<const bf16x8*>(&Vs[(jd * 16 + lm) * 72 + 32 + lk * 8]);
            o[jd] = MFMA(pa0, v0, o[jd]);
            o[jd] = MFMA(pa1, v1, o[jd]);
        }
        __builtin_amdgcn_s_setprio(0);
        __syncthreads();
    }

    // epilogue: reduce lrun across the 4 lk lanes once, normalize, write bf16
    float ltot = lrun;
    ltot += __shfl_xor(ltot, 16);
    ltot += __shfl_xor(ltot, 32);
    float linv = 1.f / ltot;
    int b = bh >> 4, h = bh & 15;
#pragma unroll
    for (int r = 0; r < 4; ++r) {
        int q = qbase + w * 16 + lk * 4 + r;
        float inv = __shfl(linv, lk * 4 + r);
        if (q >= SEQ) continue;
#pragma unroll
        for (int jd = 0; jd < 4; ++jd) {
            ao[((size_t)b * SEQ + q) * DIMC + h * HD + jd * 16 + lm] = f2bf(o[jd][r] * inv);
        }
    }
}

extern "C" void kernel_launch(void* const* d_in, const int* in_sizes, int n_in,
                              void* d_out, int out_size, void* d_ws, size_t ws_size,
                              hipStream_t stream) {
    const float* x      = (const float*)d_in[0];
    const float* w_qkv  = (const float*)d_in[1];
    const float* b_qkv  = (const float*)d_in[2];
    const float* w_proj = (const float*)d_in[3];
    const float* b_proj = (const float*)d_in[4];
    float* out = (float*)d_out;

    char* ws = (char*)d_ws;
    unsigned short* xb     = (unsigned short*)ws; ws += (size_t)MROWS * DIMC * 2;
    unsigned short* wqkvT  = (unsigned short*)ws; ws += (size_t)3 * DIMC * DIMC * 2;
    unsigned short* wprojT = (unsigned short*)ws; ws += (size_t)DIMC * DIMC * 2;
    unsigned short* qg     = (unsigned short*)ws; ws += (size_t)64 * SEQ * HD * 2;
    unsigned short* kg     = (unsigned short*)ws; ws += (size_t)64 * SEQ * HD * 2;
    unsigned short* vTg    = (unsigned short*)ws; ws += (size_t)64 * HD * NPAD * 2;
    unsigned short* ao     = (unsigned short*)ws; ws += (size_t)MROWS * DIMC * 2;

    // fused prep: cast x (2740) + transpose w_qkv (3072) + transpose w_proj (1024) + vpad (608)
    prep_kernel<<<dim3(7444), 256, 0, stream>>>(x, xb, w_qkv, wqkvT, w_proj, wprojT, vTg);

    // gemm1: grid 24 x 43 = 1032 blocks (divisible by 8), 1-D launch + internal swizzle
    gemm_bt_kernel<0><<<dim3(24 * 43), 512, 0, stream>>>(
        xb, wqkvT, MROWS, 3 * DIMC, DIMC, 24, b_qkv, qg, kg, vTg, nullptr);

    attn_kernel<<<dim3(8 * 88), 512, 0, stream>>>(qg, kg, vTg, ao);

    // gemm2: grid 8 x 43 = 344 blocks (divisible by 8)
    gemm_bt_kernel<1><<<dim3(8 * 43), 512, 0, stream>>>(
        ao, wprojT, MROWS, DIMC, DIMC, 8, b_proj, nullptr, nullptr, nullptr, out);
}